// Round 1
// baseline (283.511 us; speedup 1.0000x reference)
//
#include <hip/hip_runtime.h>
#include <math.h>

#define C_OLD 23
#define G 10
#define BVAL 8
#define NVAL 262144              // 2^18
#define ROWS_PER_BLOCK 256
#define BLOCK 256
#define TILE_FLOATS (ROWS_PER_BLOCK * C_OLD)   // 5888 floats = 23552 B
#define TILE_VEC4   (TILE_FLOATS / 4)          // 1472
#define FULL_VEC_ITERS (TILE_VEC4 / BLOCK)     // 5 (remainder 192)

__global__ void zero_ws_kernel(double* acc) {
    int t = threadIdx.x;
    if (t < BVAL * G) acc[t] = 0.0;
}

__global__ __launch_bounds__(BLOCK) void group_prob_sum_kernel(
        const float* __restrict__ in, double* __restrict__ acc) {
    __shared__ float tile[TILE_FLOATS];
    __shared__ float wpart[BLOCK / 64][G];

    const int tid = threadIdx.x;
    const long long row0 = (long long)blockIdx.x * ROWS_PER_BLOCK;

    // ---- coalesced float4 staging: tile is 16B-aligned per block ----
    const float4* __restrict__ src = (const float4*)(in + row0 * C_OLD);
    float4* dst = (float4*)tile;
    #pragma unroll
    for (int i = 0; i < FULL_VEC_ITERS; ++i)
        dst[tid + i * BLOCK] = src[tid + i * BLOCK];
    {
        int rem = tid + FULL_VEC_ITERS * BLOCK;
        if (rem < TILE_VEC4) dst[rem] = src[rem];
    }
    __syncthreads();

    // ---- per-row group sums + normalize (stride 23 LDS reads: <=2-way, free) ----
    const float* row = tile + tid * C_OLD;
    float s0 = row[0] + row[1];
    float s1 = row[2] + row[3];
    float s2 = row[4] + row[5] + row[6];
    float s3 = row[7] + row[8];
    float s4 = row[9] + row[10] + row[11];
    float s5 = row[12] + row[13];
    float s6 = row[14] + row[15] + row[16];
    float s7 = row[17] + row[18];
    float s8 = row[19] + row[20];
    float s9 = row[21] + row[22];
    float tot = ((s0 + s1) + (s2 + s3)) + ((s4 + s5) + (s6 + s7)) + (s8 + s9);
    float inv = 1.0f / tot;

    float p[G];
    p[0] = s0 * inv; p[1] = s1 * inv; p[2] = s2 * inv; p[3] = s3 * inv;
    p[4] = s4 * inv; p[5] = s5 * inv; p[6] = s6 * inv; p[7] = s7 * inv;
    p[8] = s8 * inv; p[9] = s9 * inv;

    // ---- wave (64-lane) shuffle reduction for each group ----
    #pragma unroll
    for (int g = 0; g < G; ++g) {
        float v = p[g];
        #pragma unroll
        for (int off = 32; off > 0; off >>= 1)
            v += __shfl_down(v, off, 64);
        p[g] = v;
    }

    const int wave = tid >> 6;
    const int lane = tid & 63;
    if (lane == 0) {
        #pragma unroll
        for (int g = 0; g < G; ++g) wpart[wave][g] = p[g];
    }
    __syncthreads();

    if (tid < G) {
        float sum = wpart[0][tid] + wpart[1][tid] + wpart[2][tid] + wpart[3][tid];
        const int b = (int)(row0 >> 18);   // N = 2^18, ROWS_PER_BLOCK divides N
        atomicAdd(&acc[b * G + tid], (double)sum);
    }
}

__global__ void finalize_kernel(const double* __restrict__ acc,
                                const float* __restrict__ tgt,
                                float* __restrict__ out) {
    __shared__ double red[128];
    const int t = threadIdx.x;
    double term = 0.0;
    if (t < BVAL * G) {
        double avg = acc[t] / (double)NVAL;     // mean prob over N
        double tv = (double)tgt[t];
        term = tv * (log(tv) - log(avg));
    }
    red[t] = term;
    __syncthreads();
    #pragma unroll
    for (int s = 64; s > 0; s >>= 1) {
        if (t < s) red[t] += red[t + s];
        __syncthreads();
    }
    if (t == 0) out[0] = (float)(red[0] / (double)(G * BVAL));
}

extern "C" void kernel_launch(void* const* d_in, const int* in_sizes, int n_in,
                              void* d_out, int out_size, void* d_ws, size_t ws_size,
                              hipStream_t stream) {
    const float* inputs  = (const float*)d_in[0];   // [8, 262144, 23] f32
    const float* targets = (const float*)d_in[1];   // [8, 10] f32
    float* out = (float*)d_out;                     // scalar f32
    double* acc = (double*)d_ws;                    // 80 doubles

    zero_ws_kernel<<<1, 128, 0, stream>>>(acc);

    const long long total_rows = (long long)BVAL * NVAL;          // 2,097,152
    const int nblocks = (int)(total_rows / ROWS_PER_BLOCK);       // 8192
    group_prob_sum_kernel<<<nblocks, BLOCK, 0, stream>>>(inputs, acc);

    finalize_kernel<<<1, 128, 0, stream>>>(acc, targets, out);
}

// Round 2
// 270.042 us; speedup vs baseline: 1.0499x; 1.0499x over previous
//
#include <hip/hip_runtime.h>
#include <math.h>

#define C_OLD 23
#define G 10
#define BVAL 8
#define NVAL 262144                 // 2^18 rows per b
#define BLOCK 256
#define ROWS_PER_TILE 256
#define TILES 8
#define BLOCKS_PER_B 128            // 128 blocks * 8 tiles * 256 rows = 262144
#define TILE_FLOATS (ROWS_PER_TILE * C_OLD)   // 5888 floats = 23552 B
#define TILE_VEC4   (TILE_FLOATS / 4)         // 1472
#define FULL_VEC_ITERS (TILE_VEC4 / BLOCK)    // 5, remainder 192

// ws layout: part[(b*G + g) * BLOCKS_PER_B + blk]  -> 80*128 floats = 40 KB
__global__ __launch_bounds__(BLOCK) void group_prob_partial_kernel(
        const float* __restrict__ in, float* __restrict__ part) {
    __shared__ float tile[TILE_FLOATS];
    __shared__ float wpart[BLOCK / 64][G];

    const int tid = threadIdx.x;
    const int b   = blockIdx.x / BLOCKS_PER_B;
    const int blk = blockIdx.x % BLOCKS_PER_B;
    const long long rowBase = (long long)b * NVAL
                            + (long long)blk * (ROWS_PER_TILE * TILES);

    float acc[G];
    #pragma unroll
    for (int g = 0; g < G; ++g) acc[g] = 0.0f;

    for (int t = 0; t < TILES; ++t) {
        // ---- coalesced float4 staging (block tile is 16B-aligned) ----
        const float4* __restrict__ src =
            (const float4*)(in + (rowBase + (long long)t * ROWS_PER_TILE) * C_OLD);
        float4* dst = (float4*)tile;
        #pragma unroll
        for (int i = 0; i < FULL_VEC_ITERS; ++i)
            dst[tid + i * BLOCK] = src[tid + i * BLOCK];
        if (tid < TILE_VEC4 - FULL_VEC_ITERS * BLOCK)
            dst[tid + FULL_VEC_ITERS * BLOCK] = src[tid + FULL_VEC_ITERS * BLOCK];
        __syncthreads();

        // ---- per-row group sums + normalize (stride-23 LDS: <=2-way, free) ----
        const float* row = tile + tid * C_OLD;
        float s0 = row[0] + row[1];
        float s1 = row[2] + row[3];
        float s2 = row[4] + row[5] + row[6];
        float s3 = row[7] + row[8];
        float s4 = row[9] + row[10] + row[11];
        float s5 = row[12] + row[13];
        float s6 = row[14] + row[15] + row[16];
        float s7 = row[17] + row[18];
        float s8 = row[19] + row[20];
        float s9 = row[21] + row[22];
        float tot = ((s0 + s1) + (s2 + s3)) + ((s4 + s5) + (s6 + s7)) + (s8 + s9);
        float inv = 1.0f / tot;
        acc[0] += s0 * inv; acc[1] += s1 * inv; acc[2] += s2 * inv;
        acc[3] += s3 * inv; acc[4] += s4 * inv; acc[5] += s5 * inv;
        acc[6] += s6 * inv; acc[7] += s7 * inv; acc[8] += s8 * inv;
        acc[9] += s9 * inv;
        __syncthreads();   // tile reused next iteration
    }

    // ---- one block reduction, amortized over 2048 rows ----
    #pragma unroll
    for (int g = 0; g < G; ++g) {
        float v = acc[g];
        #pragma unroll
        for (int off = 32; off > 0; off >>= 1)
            v += __shfl_down(v, off, 64);
        acc[g] = v;
    }
    const int wave = tid >> 6;
    const int lane = tid & 63;
    if (lane == 0) {
        #pragma unroll
        for (int g = 0; g < G; ++g) wpart[wave][g] = acc[g];
    }
    __syncthreads();
    if (tid < G) {
        float s = wpart[0][tid] + wpart[1][tid] + wpart[2][tid] + wpart[3][tid];
        part[((long long)b * G + tid) * BLOCKS_PER_B + blk] = s;
    }
}

__global__ void finalize_kernel(const float* __restrict__ part,
                                const float* __restrict__ tgt,
                                float* __restrict__ out) {
    __shared__ double red[128];
    const int t = threadIdx.x;
    double term = 0.0;
    if (t < BVAL * G) {
        double s = 0.0;
        const float* p = part + (long long)t * BLOCKS_PER_B;
        #pragma unroll 8
        for (int i = 0; i < BLOCKS_PER_B; ++i) s += (double)p[i];
        double avg = s / (double)NVAL;          // mean prob over N
        double tv  = (double)tgt[t];
        term = tv * (log(tv) - log(avg));
    }
    red[t] = term;
    __syncthreads();
    #pragma unroll
    for (int s = 64; s > 0; s >>= 1) {
        if (t < s) red[t] += red[t + s];
        __syncthreads();
    }
    if (t == 0) out[0] = (float)(red[0] / (double)(G * BVAL));
}

extern "C" void kernel_launch(void* const* d_in, const int* in_sizes, int n_in,
                              void* d_out, int out_size, void* d_ws, size_t ws_size,
                              hipStream_t stream) {
    const float* inputs  = (const float*)d_in[0];   // [8, 262144, 23] f32
    const float* targets = (const float*)d_in[1];   // [8, 10] f32
    float* out  = (float*)d_out;                    // scalar f32
    float* part = (float*)d_ws;                     // 80 * 128 floats

    group_prob_partial_kernel<<<BVAL * BLOCKS_PER_B, BLOCK, 0, stream>>>(inputs, part);
    finalize_kernel<<<1, 128, 0, stream>>>(part, targets, out);
}